// Round 10
// baseline (988.524 us; speedup 1.0000x reference)
//
#include <hip/hip_runtime.h>
#include <hip/hip_cooperative_groups.h>

namespace cg = cooperative_groups;

// ---------------------------------------------------------------------------
// SortNet: 3-layer 1x1-conv MLP (64->64->16->1) with training-mode BatchNorm
// + ReLU, per-batch top-64 over N, gather of input + score.
//
// R10: cooperative fused kernel (prep -> conv0+y0-store+stats0 -> reduce0 ->
// bn1-stream(y0)+conv1+stats1 -> reduce1) with:
//  - grid-stride phases (any grid <= 1024)
//  - occupancy-clamped coop grid + launch ERROR CHECK (R9 lesson: unchecked
//    cooperative launch failed silently)
//  - discrete-launch fallback using the exact same device functions
// Store-y0 plan: R5 measured conv0+store (90us) + bn1 (~35) < recompute
// (80+92); R5 only lost to launch gaps, which fusion removes. y0 is fp32
// (exact - bf16 could reorder ranks). Tail: k_layer2 + k_select (R8-proven).
// ---------------------------------------------------------------------------

constexpr int   B_   = 16;
constexpr int   N_   = 32768;
constexpr int   K_   = 64;            // TOP_K
constexpr long long S_ = (long long)B_ * N_;   // 524288
constexpr float EPS_ = 1e-5f;

constexpr int NT    = 8192;   // 64-position tiles (S/64)
constexpr int MAXNB = 1024;   // max fused/discrete grid (p0/p1 sized for it)
constexpr int NB2   = 256;    // k_layer2 blocks
constexpr int NBINS = 4096;   // radix bins (key >> 20)
constexpr int CAP   = 1024;   // candidates per batch

__device__ __forceinline__ unsigned key_map(float f) {
  unsigned u = __float_as_uint(f);
  return (u & 0x80000000u) ? ~u : (u | 0x80000000u);
}

// async 16B global->LDS (dest lane-linear: offset = 4*e floats = linear in lane)
__device__ __forceinline__ void gload16(const float* g, float* l) {
  __builtin_amdgcn_global_load_lds(
      (const __attribute__((address_space(1))) void*)g,
      (__attribute__((address_space(3))) void*)l, 16, 0, 0);
}

// stage one 64-pos x 64-feat tile into dst[64*64] (row-major)
__device__ __forceinline__ void stage_tile(const float* __restrict__ src,
                                           float* __restrict__ dst, int t) {
#pragma unroll
  for (int q = 0; q < 4; ++q) {
    const int e = t + q * 256;
    const int f = e >> 4, c4 = (e & 15) << 2;
    gload16(src + (long long)f * N_ + c4, dst + f * 64 + c4);
  }
}

// --------------------------- device phases ---------------------------------
__device__ __forceinline__ void phase_prep(const float* __restrict__ w0,
                                           const float* __restrict__ w1,
                                           float* __restrict__ w0T,
                                           float* __restrict__ w1T, int t) {
  for (int e = t; e < 4096; e += 256)
    w0T[(e & 63) * 64 + (e >> 6)] = w0[e];        // w0T[f][o] = w0[o][f]
  for (int e = t; e < 1024; e += 256) {
    const int o = e >> 6, c = e & 63;
    w1T[c * 16 + o] = w1[e];                      // w1T[c][o] = w1[o][c]
  }
}

// conv0 -> y0 store + stats0 partials (dbuf async staging, 1 barrier/tile);
// zeros ghist. Grid-stride over NT tiles.
__device__ void phase_conv0(const float* __restrict__ sv,
                            const float* __restrict__ w0T,
                            const float* __restrict__ b0,
                            float* __restrict__ y0,
                            float* __restrict__ p0,
                            int* __restrict__ ghist,
                            float* smem, int t, int bid, int nb) {
  const int p   = t & 63;
  const int cgq = __builtin_amdgcn_readfirstlane(t >> 6);

  for (int e = bid * 256 + t; e < B_ * NBINS; e += nb * 256) ghist[e] = 0;

  float bb[16];
#pragma unroll
  for (int j = 0; j < 16; ++j) bb[j] = b0[cgq * 16 + j];
  float s1[16], s2[16];
#pragma unroll
  for (int j = 0; j < 16; ++j) { s1[j] = 0.f; s2[j] = 0.f; }

  stage_tile(sv + ((long long)(bid >> 9) * 64) * N_ + ((bid & 511) << 6),
             smem, t);
  int cur = 0;
  for (int tile = bid; tile < NT; tile += nb) {
    __syncthreads();                       // drains DMA into smem[cur]
    const int nxt = tile + nb;
    if (nxt < NT)
      stage_tile(sv + ((long long)(nxt >> 9) * 64) * N_ + ((nxt & 511) << 6),
                 smem + (cur ^ 1) * 4096, t);

    const float* svt = smem + cur * 4096;
    float y[16];
#pragma unroll
    for (int j = 0; j < 16; ++j) y[j] = bb[j];
    for (int f = 0; f < 64; ++f) {
      const float x = svt[f * 64 + p];
      const float* wr = w0T + f * 64 + cgq * 16;   // wave-uniform -> s_load
#pragma unroll
      for (int j = 0; j < 16; ++j) y[j] = fmaf(wr[j], x, y[j]);
    }
    const int b = tile >> 9, n0 = (tile & 511) << 6;
    float* dst = y0 + ((long long)(b * 64 + cgq * 16)) * N_ + n0 + p;
#pragma unroll
    for (int j = 0; j < 16; ++j) {
      dst[(long long)j * N_] = y[j];
      s1[j] += y[j];
      s2[j] = fmaf(y[j], y[j], s2[j]);
    }
    cur ^= 1;
  }

#pragma unroll
  for (int j = 0; j < 16; ++j) {
#pragma unroll
    for (int off = 32; off; off >>= 1) {
      s1[j] += __shfl_down(s1[j], off, 64);
      s2[j] += __shfl_down(s2[j], off, 64);
    }
  }
  if (p == 0) {
    float* dst = p0 + (long long)bid * 128;
#pragma unroll
    for (int j = 0; j < 16; ++j) {
      dst[cgq * 16 + j]      = s1[j];
      dst[64 + cgq * 16 + j] = s2[j];
    }
  }
}

// reduce p0[nb][128] -> st0 (fixed order, 256 threads)
__device__ void reduce0_dev(const float* __restrict__ p0,
                            const float* __restrict__ g,
                            const float* __restrict__ bt,
                            float* __restrict__ st,
                            float* l, int t, int nb) {
  const int j = t & 127, grp = t >> 7;     // 2 groups
  float a = 0.f;
  for (int i = grp; i < nb; i += 2) a += p0[(long long)i * 128 + j];
  l[grp * 128 + j] = a;
  __syncthreads();
  if (t < 128) l[t] = l[t] + l[128 + t];
  __syncthreads();
  if (t < 64) {
    const float inv = 1.f / (float)S_;
    float mean = l[t] * inv;
    float ex2  = l[64 + t] * inv;
    float var  = ex2 - mean * mean;
    float sc   = g[t] * rsqrtf(var + EPS_);
    st[t]      = sc;
    st[64 + t] = bt[t] - mean * sc;
  }
}

// stream y0: bn0+relu -> conv1 -> y1 + stats1 partials. 1 pos/thread.
__device__ void phase_bn1(const float* __restrict__ y0,
                          const float* __restrict__ st0,
                          const float* __restrict__ w1T,
                          const float* __restrict__ b1,
                          float* __restrict__ y1,
                          float* __restrict__ p1,
                          float* smem, int t, int bid, int nb) {
  float s1[16], s2[16];
#pragma unroll
  for (int j = 0; j < 16; ++j) { s1[j] = 0.f; s2[j] = 0.f; }

  const long long stride = (long long)nb * 256;
  for (long long pos = (long long)bid * 256 + t; pos < S_; pos += stride) {
    const int b = (int)(pos >> 15);
    const int n = (int)(pos & (N_ - 1));
    const float* xp = y0 + ((long long)b * 64) * N_ + n;

    float z[16];
#pragma unroll
    for (int j = 0; j < 16; ++j) z[j] = b1[j];
#pragma unroll 8
    for (int c = 0; c < 64; ++c) {
      float v = xp[(long long)c * N_];
      float h = fmaf(v, st0[c], st0[64 + c]);
      h = h > 0.f ? h : 0.f;
      const float* wr = w1T + c * 16;              // wave-uniform -> s_load
#pragma unroll
      for (int j = 0; j < 16; ++j) z[j] = fmaf(wr[j], h, z[j]);
    }
    float* yo = y1 + ((long long)b * 16) * N_ + n;
#pragma unroll
    for (int j = 0; j < 16; ++j) {
      yo[(long long)j * N_] = z[j];
      s1[j] += z[j];
      s2[j] = fmaf(z[j], z[j], s2[j]);
    }
  }

  const int wid = t >> 6, lid = t & 63;
#pragma unroll
  for (int j = 0; j < 16; ++j) {
    float a = s1[j], q = s2[j];
#pragma unroll
    for (int off = 32; off; off >>= 1) {
      a += __shfl_down(a, off, 64);
      q += __shfl_down(q, off, 64);
    }
    if (lid == 0) { smem[wid * 32 + j] = a; smem[wid * 32 + 16 + j] = q; }
  }
  __syncthreads();
  if (t < 32)
    p1[(long long)bid * 32 + t] =
        (smem[t] + smem[32 + t]) + (smem[64 + t] + smem[96 + t]);
}

// reduce p1[nb][32] -> st1 (256 threads)
__device__ void reduce1_dev(const float* __restrict__ p1,
                            const float* __restrict__ g,
                            const float* __restrict__ bt,
                            float* __restrict__ st,
                            float* l, int t, int nb) {
  const int j = t & 31, grp = t >> 5;      // 8 groups
  float a = 0.f;
  for (int i = grp; i < nb; i += 8) a += p1[(long long)i * 32 + j];
  l[grp * 32 + j] = a;
  __syncthreads();
  if (t < 32) {
    float v = 0.f;
#pragma unroll
    for (int g2 = 0; g2 < 8; ++g2) v += l[g2 * 32 + t];
    l[t] = v;
  }
  __syncthreads();
  if (t < 16) {
    const float inv = 1.f / (float)S_;
    float mean = l[t] * inv;
    float ex2  = l[16 + t] * inv;
    float var  = ex2 - mean * mean;
    float sc   = g[t] * rsqrtf(var + EPS_);
    st[t]      = sc;
    st[16 + t] = bt[t] - mean * sc;
  }
}

// --------------------------- fused cooperative kernel ----------------------
__global__ __launch_bounds__(256, 4) void k_fused(
    const float* __restrict__ sv, const float* __restrict__ w0,
    const float* __restrict__ b0, const float* __restrict__ w1,
    const float* __restrict__ b1, const float* __restrict__ g0,
    const float* __restrict__ bt0, const float* __restrict__ g1,
    const float* __restrict__ bt1, float* __restrict__ w0T,
    float* __restrict__ w1T, float* __restrict__ st0,
    float* __restrict__ st1, float* __restrict__ p0,
    float* __restrict__ p1, float* __restrict__ y0,
    float* __restrict__ y1, int* __restrict__ ghist) {
  __shared__ float smem[8192];             // 32 KB, reused per phase
  const int t = threadIdx.x, bid = blockIdx.x, nb = gridDim.x;
  cg::grid_group grid = cg::this_grid();

  if (bid == 0) phase_prep(w0, w1, w0T, w1T, t);
  __threadfence();
  grid.sync();

  phase_conv0(sv, w0T, b0, y0, p0, ghist, smem, t, bid, nb);
  __threadfence();
  grid.sync();

  if (bid == 0) reduce0_dev(p0, g0, bt0, st0, smem, t, nb);
  __threadfence();
  grid.sync();

  phase_bn1(y0, st0, w1T, b1, y1, p1, smem, t, bid, nb);
  __threadfence();
  grid.sync();

  if (bid == 0) reduce1_dev(p1, g1, bt1, st1, smem, t, nb);
}

// --------------------------- fallback wrappers -----------------------------
__global__ __launch_bounds__(256) void k_prep_w(const float* w0, const float* w1,
                                                float* w0T, float* w1T) {
  phase_prep(w0, w1, w0T, w1T, threadIdx.x);
}
__global__ __launch_bounds__(256, 4) void k_phA(const float* sv, const float* w0T,
                                                const float* b0, float* y0,
                                                float* p0, int* ghist) {
  __shared__ float smem[8192];
  phase_conv0(sv, w0T, b0, y0, p0, ghist, smem, threadIdx.x, blockIdx.x,
              gridDim.x);
}
__global__ __launch_bounds__(256) void k_red0w(const float* p0, const float* g,
                                               const float* bt, float* st, int nb) {
  __shared__ float l[256];
  reduce0_dev(p0, g, bt, st, l, threadIdx.x, nb);
}
__global__ __launch_bounds__(256, 4) void k_phB(const float* y0, const float* st0,
                                                const float* w1T, const float* b1,
                                                float* y1, float* p1) {
  __shared__ float smem[128];
  phase_bn1(y0, st0, w1T, b1, y1, p1, smem, threadIdx.x, blockIdx.x, gridDim.x);
}
__global__ __launch_bounds__(256) void k_red1w(const float* p1, const float* g,
                                               const float* bt, float* st, int nb) {
  __shared__ float l[256];
  reduce1_dev(p1, g, bt, st, l, threadIdx.x, nb);
}

// --------------------------- k_layer2 --------------------------------------
__global__ __launch_bounds__(1024) void k_layer2(const float* __restrict__ y1,
                                                 const float* __restrict__ st1,
                                                 const float* __restrict__ w2,
                                                 const float* __restrict__ b2,
                                                 float* __restrict__ y2,
                                                 float* __restrict__ p2,
                                                 int* __restrict__ ghist) {
  __shared__ int hist[NBINS];
  __shared__ float ls[16], lq[16];
  const int t   = threadIdx.x;
  const int blk = blockIdx.x;
  const int b   = blk >> 4;
  const int n0  = ((blk & 15) << 11) | (t << 1);

#pragma unroll
  for (int i = 0; i < NBINS / 1024; ++i) hist[t + i * 1024] = 0;

  float sc[16], sh[16], w[16];
#pragma unroll
  for (int c = 0; c < 16; ++c) { sc[c] = st1[c]; sh[c] = st1[16 + c]; w[c] = w2[c]; }
  const float bias = b2[0];

  float a0 = bias, a1 = bias;
  const float* base = y1 + ((long long)b * 16) * N_ + n0;
#pragma unroll
  for (int c = 0; c < 16; ++c) {
    float2 v = *(const float2*)(base + (long long)c * N_);
    float h;
    h = fmaf(v.x, sc[c], sh[c]); h = h > 0.f ? h : 0.f; a0 = fmaf(w[c], h, a0);
    h = fmaf(v.y, sc[c], sh[c]); h = h > 0.f ? h : 0.f; a1 = fmaf(w[c], h, a1);
  }
  float2 o; o.x = a0; o.y = a1;
  *(float2*)(y2 + (long long)b * N_ + n0) = o;

  __syncthreads();

  atomicAdd(&hist[key_map(a0) >> 20], 1);
  atomicAdd(&hist[key_map(a1) >> 20], 1);

  float ss = a0 + a1;
  float sq = fmaf(a0, a0, a1 * a1);
#pragma unroll
  for (int off = 32; off; off >>= 1) {
    ss += __shfl_down(ss, off, 64);
    sq += __shfl_down(sq, off, 64);
  }
  const int wid = t >> 6, lid = t & 63;
  if (lid == 0) { ls[wid] = ss; lq[wid] = sq; }
  __syncthreads();
  if (t == 0) {
    float Sv = 0.f, Qv = 0.f;
#pragma unroll
    for (int i = 0; i < 16; ++i) { Sv += ls[i]; Qv += lq[i]; }
    p2[blk * 2 + 0] = Sv;
    p2[blk * 2 + 1] = Qv;
  }
#pragma unroll
  for (int i = 0; i < NBINS / 1024; ++i) {
    int v = hist[t + i * 1024];
    if (v) atomicAdd(&ghist[b * NBINS + t + i * 1024], v);
  }
}

// --------------------------- k_select --------------------------------------
__global__ __launch_bounds__(1024) void k_select(const float* __restrict__ y2,
                                                 const int* __restrict__ ghist,
                                                 const float* __restrict__ p2,
                                                 const float* __restrict__ g2,
                                                 const float* __restrict__ bt2,
                                                 const float* __restrict__ inp,
                                                 float* __restrict__ out) {
  __shared__ int hl[NBINS + NBINS / 64];
  __shared__ float sred[512];
  __shared__ unsigned long long cand[CAP];
  __shared__ int lcnt;
  __shared__ int sT;
  __shared__ float s2v[2];
  __shared__ int   idxs[K_];
  __shared__ float scores[K_];

  const int t = threadIdx.x, b = blockIdx.x;
  const int* h = ghist + b * NBINS;
  for (int i = t; i < NBINS; i += 1024) hl[i + (i >> 6)] = h[i];
  if (t < 512) sred[t] = p2[t];
  if (t == 0) lcnt = 0;
  __syncthreads();
  for (int s = 256; s >= 2; s >>= 1) {
    if (t < s) sred[t] += sred[t + s];
    __syncthreads();
  }
  if (t == 0) {
    const float inv = 1.f / (float)S_;
    float mean = sred[0] * inv;
    float var  = sred[1] * inv - mean * mean;
    float scv  = g2[0] * rsqrtf(var + EPS_);
    s2v[0] = scv;
    s2v[1] = bt2[0] - mean * scv;
  }
  if (t < 64) {
    const int l = t;
    int s = 0;
    for (int j = 0; j < 64; ++j) s += hl[(l * 64 + j) + l];
    int Sv = s;
#pragma unroll
    for (int off = 1; off < 64; off <<= 1) {
      int v = __shfl_down(Sv, off, 64);
      if (l + off < 64) Sv += v;
    }
    unsigned long long m = __ballot(Sv >= K_);
    const int lstar = 63 - __builtin_clzll(m);
    const int tailS = (lstar < 63) ? __shfl(Sv, lstar + 1, 64) : 0;
    int Tj = hl[(lstar * 64 + l) + lstar];
#pragma unroll
    for (int off = 1; off < 64; off <<= 1) {
      int v = __shfl_down(Tj, off, 64);
      if (l + off < 64) Tj += v;
    }
    const int cge = Tj + tailS;
    unsigned long long m2 = __ballot(cge >= K_);
    const int jstar = 63 - __builtin_clzll(m2);
    if (l == 0) sT = lstar * 64 + jstar;
  }
  __syncthreads();

  const int T = sT;
  const float* yrow = y2 + (long long)b * N_;
  for (int it = 0; it < 8; ++it) {
    const int n0 = (it << 12) | (t << 2);
    float4 v = *(const float4*)(yrow + n0);
#define DO_CAND(comp, off)                                                    \
    {                                                                         \
      unsigned u = key_map(comp);                                             \
      if ((int)(u >> 20) >= T) {                                              \
        int slot = atomicAdd(&lcnt, 1);                                       \
        if (slot < CAP)                                                       \
          cand[slot] = ((unsigned long long)u << 32) |                        \
                       (unsigned)(N_ - 1 - (n0 + off));                       \
      }                                                                       \
    }
    DO_CAND(v.x, 0) DO_CAND(v.y, 1) DO_CAND(v.z, 2) DO_CAND(v.w, 3)
#undef DO_CAND
  }
  __syncthreads();

  if (t < 64) {
    const int l = t;
    int cn = lcnt;
    if (cn > CAP) cn = CAP;
    unsigned long long k[16];
#pragma unroll
    for (int r = 0; r < 16; ++r) {
      int i = l + r * 64;
      k[r] = (i < cn) ? cand[i] : 0ull;
    }
    unsigned long long curk = 0ull;
#pragma unroll
    for (int r = 0; r < 16; ++r) curk = k[r] > curk ? k[r] : curk;

    int myidx = 0;
    unsigned mymap = 0;
    for (int r = 0; r < K_; ++r) {
      unsigned long long m = curk;
#pragma unroll
      for (int off = 32; off; off >>= 1) {
        unsigned long long o = __shfl_xor(m, off, 64);
        m = o > m ? o : m;
      }
      if (r == l) {
        myidx = N_ - 1 - (int)(m & 0xffffffffu);
        mymap = (unsigned)(m >> 32);
      }
      if (curk == m) {
#pragma unroll
        for (int r2 = 0; r2 < 16; ++r2)
          if (k[r2] == m) k[r2] = 0ull;
        unsigned long long c2 = 0ull;
#pragma unroll
        for (int r2 = 0; r2 < 16; ++r2) c2 = k[r2] > c2 ? k[r2] : c2;
        curk = c2;
      }
    }
    unsigned u = mymap;
    u = (u & 0x80000000u) ? (u & 0x7fffffffu) : ~u;
    float v = __uint_as_float(u);
    float scv = fmaf(v, s2v[0], s2v[1]);
    scores[l] = scv > 0.f ? scv : 0.f;
    idxs[l]   = myidx;
  }
  __syncthreads();

  const float* ib = inp + ((long long)b * 64) * N_;
  for (int e = t; e < 65 * 64; e += 1024) {
    const int f = e >> 6, k = e & 63;
    out[((long long)b * 65 + f) * 64 + k] =
        (f < 64) ? ib[(long long)f * N_ + idxs[k]] : scores[k];
  }
  if (t < K_) out[(long long)B_ * 65 * 64 + b * 64 + t] = (float)idxs[t];
}

// --------------------------- launch ----------------------------------------
extern "C" void kernel_launch(void* const* d_in, const int* in_sizes, int n_in,
                              void* d_out, int out_size, void* d_ws, size_t ws_size,
                              hipStream_t stream) {
  const float* sv  = (const float*)d_in[0];
  const float* inp = (const float*)d_in[1];
  const float* w0  = (const float*)d_in[2];
  const float* b0  = (const float*)d_in[3];
  const float* w1  = (const float*)d_in[4];
  const float* b1  = (const float*)d_in[5];
  const float* w2  = (const float*)d_in[6];
  const float* b2  = (const float*)d_in[7];
  const float* g0  = (const float*)d_in[8];
  const float* bt0 = (const float*)d_in[9];
  const float* g1  = (const float*)d_in[10];
  const float* bt1 = (const float*)d_in[11];
  const float* g2  = (const float*)d_in[12];
  const float* bt2 = (const float*)d_in[13];
  float* out = (float*)d_out;

  float* ws  = (float*)d_ws;
  float* y0  = ws;                                    // S*64 = 33,554,432
  float* y1  = y0 + (size_t)S_ * 64;                  // S*16 =  8,388,608
  float* y2  = y1 + (size_t)S_ * 16;                  // S    =    524,288
  float* p0  = y2 + (size_t)S_;                       // 1024*128 = 131,072
  float* p1  = p0 + (size_t)MAXNB * 128;              // 1024*32  =  32,768
  float* p2  = p1 + (size_t)MAXNB * 32;               // 512
  float* st0 = p2 + 512;                              // 128
  float* st1 = st0 + 128;                             // 32
  float* w0T = st1 + 32;                              // 4096
  float* w1T = w0T + 4096;                            // 1024
  int*   ghist = (int*)(w1T + 1024);                  // 16*4096 ints
  // total ~170.8 MB (R5 proved ws_size covers the y0-store layout)

  int dev = 0, coop = 0, ncu = 0, maxb = 0;
  hipGetDevice(&dev);
  hipDeviceGetAttribute(&coop, hipDeviceAttributeCooperativeLaunch, dev);
  hipDeviceGetAttribute(&ncu, hipDeviceAttributeMultiprocessorCount, dev);
  hipOccupancyMaxActiveBlocksPerMultiprocessor(&maxb, (const void*)k_fused,
                                               256, 0);

  bool fused_done = false;
  if (coop && ncu > 0 && maxb > 0) {
    int grid = ncu * maxb;
    if (grid > MAXNB) grid = MAXNB;
    if (grid >= 64) {
      void* args[] = {(void*)&sv,  (void*)&w0,  (void*)&b0,  (void*)&w1,
                      (void*)&b1,  (void*)&g0,  (void*)&bt0, (void*)&g1,
                      (void*)&bt1, (void*)&w0T, (void*)&w1T, (void*)&st0,
                      (void*)&st1, (void*)&p0,  (void*)&p1,  (void*)&y0,
                      (void*)&y1,  (void*)&ghist};
      if (hipLaunchCooperativeKernel((void*)k_fused, dim3(grid), dim3(256),
                                     args, 0, stream) == hipSuccess)
        fused_done = true;
    }
  }
  if (!fused_done) {
    k_prep_w<<<1,     256, 0, stream>>>(w0, w1, w0T, w1T);
    k_phA   <<<MAXNB, 256, 0, stream>>>(sv, w0T, b0, y0, p0, ghist);
    k_red0w <<<1,     256, 0, stream>>>(p0, g0, bt0, st0, MAXNB);
    k_phB   <<<MAXNB, 256, 0, stream>>>(y0, st0, w1T, b1, y1, p1);
    k_red1w <<<1,     256, 0, stream>>>(p1, g1, bt1, st1, MAXNB);
  }

  k_layer2<<<NB2, 1024, 0, stream>>>(y1, st1, w2, b2, y2, p2, ghist);
  k_select<<<B_,  1024, 0, stream>>>(y2, ghist, p2, g2, bt2, inp, out);
}